// Round 1
// baseline (7080.480 us; speedup 1.0000x reference)
//
#include <hip/hip_runtime.h>
#include <hip/hip_bf16.h>

// GRU_teach round 0: correctness-first persistent VALU kernel.
// - Rows are independent -> each block owns 16 rows for all 200 steps, no grid sync.
// - Device-side dtype sniffing (ws flags): float arrays bf16 vs fp32; mask bf16/fp32/int32/uint8.
// - Weights repacked (pre-pass) into k-blocked bf16 layout [kb][N][8] in ws for coalesced uint4 loads.
// - y/mask/out staged through registers in t-chunks of 4 (layout [B,64,T] is t-contiguous).
// - GEMM1/2: wave owns 4 rows, lane owns 5 n-slots; x via LDS wave-broadcast float4 reads;
//   weight loads software-pipelined (prefetch next kb).

#define BSZ   4096
#define XD    128
#define YD    64
#define TT    200
#define LATD  100
#define NH3   300
#define RPB   16
#define NBLK  (BSZ / RPB)

typedef unsigned short u16;
typedef unsigned int   u32;

__device__ __forceinline__ float bf_lo(u32 u){ return __uint_as_float(u << 16); }
__device__ __forceinline__ float bf_hi(u32 u){ return __uint_as_float(u & 0xFFFF0000u); }
__device__ __forceinline__ u16 f2bf(float f){
  u32 u = __float_as_uint(f);
  u32 r = (u + 0x7FFFu + ((u >> 16) & 1u)) >> 16;   // RNE
  return (u16)r;
}
__device__ __forceinline__ float loadf(const void* p, size_t i, int fmode){
  return (fmode == 0) ? __uint_as_float(((u32)((const u16*)p)[i]) << 16)
                      : ((const float*)p)[i];
}

// dot of fp32 LDS row (KB*8 floats, padded with zeros) with k-blocked bf16 weights, column n of N
__device__ __forceinline__ float dotblk(const float* xr, const u16* wb, int n, int N, int KB){
  float a = 0.f;
  const uint4* wp = (const uint4*)wb;
  #pragma unroll
  for (int kb = 0; kb < KB; ++kb){
    uint4 u = wp[kb * N + n];
    const float4* xp = (const float4*)(xr + (kb << 3));
    float4 x0 = xp[0], x1 = xp[1];
    a += x0.x*bf_lo(u.x) + x0.y*bf_hi(u.x) + x0.z*bf_lo(u.y) + x0.w*bf_hi(u.y);
    a += x1.x*bf_lo(u.z) + x1.y*bf_hi(u.z) + x1.z*bf_lo(u.w) + x1.w*bf_hi(u.w);
  }
  return a;
}

// ---------------- dtype detection ----------------
__global__ void detect_kernel(const void* mask, const void* x, int* flags){
  __shared__ int cnt[4];
  if (threadIdx.x < 4) cnt[threadIdx.x] = 0;
  __syncthreads();
  if (blockIdx.x == 0){
    // mask mode: 0=bf16, 1=fp32, 2=int32, 3=uint8
    const unsigned char* p = (const unsigned char*)mask;
    int c0=0, c1=0, c2=0, c3=0;
    for (int i = threadIdx.x; i < 4096; i += 256){
      unsigned char b = p[i];
      if (b == 0x3F && (i & 3) == 1) c0++;       // bf16 "1.0" high byte at odd-of-pair
      if (b == 0x3F && (i & 3) == 3) c1++;       // fp32 "1.0f" top byte
      if (b == 1    && (i & 3) != 0) c2++;       // uint8 ones off int32 alignment
      if (b == 1)                    c3++;       // int32 ones
    }
    atomicAdd(&cnt[0], c0); atomicAdd(&cnt[1], c1);
    atomicAdd(&cnt[2], c2); atomicAdd(&cnt[3], c3);
    __syncthreads();
    if (threadIdx.x == 0){
      int mm;
      if      (cnt[0] > 0) mm = 0;
      else if (cnt[1] > 0) mm = 1;
      else if (cnt[2] > 0) mm = 3;
      else if (cnt[3] > 0) mm = 2;
      else                 mm = 0;
      flags[1] = mm;
    }
  } else {
    // float mode: 0=bf16, 1=fp32.  fp32 low-mantissa halves look like huge bf16 exponents.
    const u16* u = (const u16*)x;
    int c = 0;
    for (int i = threadIdx.x; i < 4096; i += 256){
      int ex = (u[i] >> 7) & 0xFF;
      if (ex >= 147) c++;                         // |v| > ~1e6 as bf16
    }
    atomicAdd(&cnt[0], c);
    __syncthreads();
    if (threadIdx.x == 0) flags[0] = (cnt[0] > 32) ? 1 : 0;
  }
}

// ---------------- weight repack: [K][N] -> blocked bf16 [kb][N][8], k zero-padded ----------------
struct WtP { const void* src[7]; u16* dst[7]; const int* flags; };

__global__ void wtrans_kernel(WtP a){
  const int Ks[7]  = {128, 100, 100, 100, 128, 100, 100};
  const int Ns[7]  = {300, 300, 100,  64, 100, 100,  50};
  const int KBs[7] = { 16,  13,  13,  13,  16,  13,  13};
  int m   = blockIdx.x >> 3;
  int sub = blockIdx.x & 7;
  int K = Ks[m], N = Ns[m], KB = KBs[m];
  const void* src = a.src[m];
  u16* dst = a.dst[m];
  int fmode = a.flags[0];
  int E = KB * N * 8;
  for (int e = sub*256 + threadIdx.x; e < E; e += 8*256){
    int idx = e >> 3, kc = e & 7;
    int n = idx % N, kb = idx / N;
    int k = kb*8 + kc;
    float v = (k < K) ? loadf(src, (size_t)k * N + n, fmode) : 0.f;
    dst[e] = f2bf(v);
  }
}

// ---------------- main persistent kernel ----------------
struct MainP {
  const void *x, *y, *mask;
  const void *bmu1, *bmu2, *bih, *bhh, *bl1, *bl2, *bc1, *bc2, *wc2;
  const u16 *Wih, *Whh, *Wl1, *Wl2, *Wmu1, *Wmu2, *Wc1;
  const int* flags;
  void* out;
};

__global__ __launch_bounds__(256, 1) void gru_main(MainP P){
  __shared__ float xil[RPB][128];     // interleaved (y_in, m) fp32
  __shared__ float hS [RPB][104];     // hidden state, zero-padded
  __shared__ float Srz[RPB][200];     // r|z pre-activations
  __shared__ float gxn[RPB][104];
  __shared__ float ghn[RPB][104];
  __shared__ float hn2[RPB][104];     // tanh(h@Wl1+bl1), zero-padded
  __shared__ u16   oS [RPB][64][4];   // out window (bf16)
  __shared__ float bih_s[304], bhh_s[304];
  __shared__ float bl1_s[104], bmu1_s[104], bmu2_s[104];
  __shared__ float bl2_s[64], bc1_s[64], wc2_s[64];

  const int tid  = threadIdx.x;
  const int row0 = blockIdx.x * RPB;
  const int fmode = P.flags[0];
  const int mmode = P.flags[1];

  for (int i = tid; i < RPB*104; i += 256){
    (&hS[0][0])[i]  = 0.f;
    (&hn2[0][0])[i] = 0.f;
  }
  for (int i = tid; i < 304; i += 256){
    bih_s[i] = (i < 300) ? loadf(P.bih, i, fmode) : 0.f;
    bhh_s[i] = (i < 300) ? loadf(P.bhh, i, fmode) : 0.f;
  }
  if (tid < 104){
    bl1_s[tid]  = (tid < 100) ? loadf(P.bl1,  tid, fmode) : 0.f;
    bmu1_s[tid] = (tid < 100) ? loadf(P.bmu1, tid, fmode) : 0.f;
    bmu2_s[tid] = (tid < 100) ? loadf(P.bmu2, tid, fmode) : 0.f;
  }
  if (tid < 64){
    bl2_s[tid] = loadf(P.bl2, tid, fmode);
    bc1_s[tid] = (tid < 50) ? loadf(P.bc1, tid, fmode) : 0.f;
    wc2_s[tid] = (tid < 50) ? loadf(P.wc2, tid, fmode) : 0.f;
  }
  __syncthreads();

  // ---- h0 = tanh(x@Wmu1+bmu1)@Wmu2+bmu2 ----
  for (int p = 0; p < 2; ++p){
    int idx = tid + (p << 8);           // 512 quads of x
    int r = idx >> 5, kq = idx & 31;
    size_t base = ((size_t)(row0 + r) << 7) + ((size_t)kq << 2);
    float v0, v1, v2, v3;
    if (fmode == 0){
      uint2 u = *(const uint2*)((const u16*)P.x + base);
      v0 = bf_lo(u.x << 16 >> 16 << 16), v1 = bf_hi(u.x), v2 = bf_lo(u.y << 16 >> 16 << 16), v3 = bf_hi(u.y);
      v0 = __uint_as_float(u.x << 16);
      v2 = __uint_as_float(u.y << 16);
    } else {
      float4 f = *(const float4*)((const float*)P.x + base);
      v0 = f.x; v1 = f.y; v2 = f.z; v3 = f.w;
    }
    float* d = &xil[r][kq << 2];
    d[0] = v0; d[1] = v1; d[2] = v2; d[3] = v3;
  }
  __syncthreads();
  for (int p = 0; p < 7; ++p){
    int idx = tid + (p << 8);
    if (idx < RPB*100){
      int r = idx / 100, j = idx - r*100;
      hn2[r][j] = tanhf(bmu1_s[j] + dotblk(&xil[r][0], P.Wmu1, j, 100, 16));
    }
  }
  __syncthreads();
  for (int p = 0; p < 7; ++p){
    int idx = tid + (p << 8);
    if (idx < RPB*100){
      int r = idx / 100, j = idx - r*100;
      hS[r][j] = bmu2_s[j] + dotblk(&hn2[r][0], P.Wmu2, j, 100, 13);
    }
  }
  __syncthreads();

  uint2 y_pack[4];
  u32 m_bits = 0;
  float yprev[4] = {0.f, 0.f, 0.f, 0.f};
  const int wv  = tid >> 6;             // wave id -> rows 4w..4w+3
  const int ln  = tid & 63;             // lane -> n slots ln+64s
  const int r0w = wv << 2;

  for (int t = 0; t < TT; ++t){
    const int tc = t & 3;
    if (tc == 0){
      if (t > 0){
        int tw = t - 4;                  // flush previous window (same-thread data, no sync needed)
        #pragma unroll
        for (int p = 0; p < 4; ++p){
          int idx = tid + (p << 8);
          int r = idx >> 6, d = idx & 63;
          size_t base = ((size_t)(row0 + r)*64 + d)*200 + tw;
          if (fmode == 0){
            uint2 v = *(const uint2*)&oS[r][d][0];
            *(uint2*)((u16*)P.out + base) = v;
          } else {
            float4 f;
            f.x = __uint_as_float((u32)oS[r][d][0] << 16);
            f.y = __uint_as_float((u32)oS[r][d][1] << 16);
            f.z = __uint_as_float((u32)oS[r][d][2] << 16);
            f.w = __uint_as_float((u32)oS[r][d][3] << 16);
            *(float4*)((float*)P.out + base) = f;
          }
        }
      }
      m_bits = 0;
      #pragma unroll
      for (int p = 0; p < 4; ++p){       // stage y + mask for t..t+3 into registers
        int idx = tid + (p << 8);
        int r = idx >> 6, d = idx & 63;
        size_t base = ((size_t)(row0 + r)*64 + d)*200 + t;
        if (fmode == 0){
          y_pack[p] = *(const uint2*)((const u16*)P.y + base);
        } else {
          float4 f = *(const float4*)((const float*)P.y + base);
          uint2 u;
          u.x = (u32)f2bf(f.x) | ((u32)f2bf(f.y) << 16);
          u.y = (u32)f2bf(f.z) | ((u32)f2bf(f.w) << 16);
          y_pack[p] = u;
        }
        u32 mb = 0;
        if (mmode == 0){
          uint2 u = *(const uint2*)((const u16*)P.mask + base);
          mb = ((u.x & 0xFFFFu) ? 1u:0u) | ((u.x >> 16) ? 2u:0u)
             | ((u.y & 0xFFFFu) ? 4u:0u) | ((u.y >> 16) ? 8u:0u);
        } else if (mmode == 1){
          float4 f = *(const float4*)((const float*)P.mask + base);
          mb = (f.x!=0.f?1u:0u)|(f.y!=0.f?2u:0u)|(f.z!=0.f?4u:0u)|(f.w!=0.f?8u:0u);
        } else if (mmode == 2){
          int4 v = *(const int4*)((const int*)P.mask + base);
          mb = (v.x?1u:0u)|(v.y?2u:0u)|(v.z?4u:0u)|(v.w?8u:0u);
        } else {
          u32 u = *(const u32*)((const unsigned char*)P.mask + base);
          mb = ((u&0xFFu)?1u:0u)|((u&0xFF00u)?2u:0u)|((u&0xFF0000u)?4u:0u)|((u&0xFF000000u)?8u:0u);
        }
        m_bits |= mb << (p << 2);
      }
    }

    // stage1: build x_il (teacher forcing select)
    #pragma unroll
    for (int p = 0; p < 4; ++p){
      int idx = tid + (p << 8);
      int r = idx >> 6, d = idx & 63;
      u32 word = (tc & 2) ? y_pack[p].y : y_pack[p].x;
      float yv = (tc & 1) ? bf_hi(word) : __uint_as_float(word << 16);
      bool mv = (m_bits >> ((p << 2) | tc)) & 1u;
      float yin = mv ? yv : yprev[p];
      *(float2*)&xil[r][d << 1] = make_float2(yin, mv ? 1.f : 0.f);
    }
    __syncthreads();

    // stage2: gx = x_il@Wih, gh = h@Whh   (wave: 4 rows; lane: 5 n-slots)
    {
      float a1[5][4], a2[5][4];
      #pragma unroll
      for (int s = 0; s < 5; ++s)
        #pragma unroll
        for (int r = 0; r < 4; ++r){ a1[s][r] = 0.f; a2[s][r] = 0.f; }

      // GEMM1 (KB=16) with prefetch
      {
        uint4 uc[5], un[5];
        #pragma unroll
        for (int s = 0; s < 5; ++s){
          int n = ln + (s << 6);
          uc[s] = (s < 4 || n < NH3) ? *(const uint4*)(P.Wih + ((size_t)n << 3))
                                     : make_uint4(0u,0u,0u,0u);
          un[s] = uc[s];
        }
        for (int kb = 0; kb < 16; ++kb){
          if (kb < 15){
            #pragma unroll
            for (int s = 0; s < 5; ++s){
              int n = ln + (s << 6);
              un[s] = (s < 4 || n < NH3) ? *(const uint4*)(P.Wih + ((size_t)((kb+1)*NH3 + n) << 3))
                                         : make_uint4(0u,0u,0u,0u);
            }
          }
          float4 xa[4], xb[4];
          #pragma unroll
          for (int r = 0; r < 4; ++r){
            const float4* xp = (const float4*)&xil[r0w + r][kb << 3];
            xa[r] = xp[0]; xb[r] = xp[1];
          }
          #pragma unroll
          for (int s = 0; s < 5; ++s){
            uint4 u = uc[s];
            float w0=bf_lo(u.x), w1=bf_hi(u.x), w2=bf_lo(u.y), w3=bf_hi(u.y);
            float w4=bf_lo(u.z), w5=bf_hi(u.z), w6=bf_lo(u.w), w7=bf_hi(u.w);
            #pragma unroll
            for (int r = 0; r < 4; ++r){
              a1[s][r] += xa[r].x*w0 + xa[r].y*w1 + xa[r].z*w2 + xa[r].w*w3
                        + xb[r].x*w4 + xb[r].y*w5 + xb[r].z*w6 + xb[r].w*w7;
            }
          }
          #pragma unroll
          for (int s = 0; s < 5; ++s) uc[s] = un[s];
        }
      }
      // GEMM2 (KB=13) with prefetch
      {
        uint4 uc[5], un[5];
        #pragma unroll
        for (int s = 0; s < 5; ++s){
          int n = ln + (s << 6);
          uc[s] = (s < 4 || n < NH3) ? *(const uint4*)(P.Whh + ((size_t)n << 3))
                                     : make_uint4(0u,0u,0u,0u);
          un[s] = uc[s];
        }
        for (int kb = 0; kb < 13; ++kb){
          if (kb < 12){
            #pragma unroll
            for (int s = 0; s < 5; ++s){
              int n = ln + (s << 6);
              un[s] = (s < 4 || n < NH3) ? *(const uint4*)(P.Whh + ((size_t)((kb+1)*NH3 + n) << 3))
                                         : make_uint4(0u,0u,0u,0u);
            }
          }
          float4 xa[4], xb[4];
          #pragma unroll
          for (int r = 0; r < 4; ++r){
            const float4* xp = (const float4*)&hS[r0w + r][kb << 3];
            xa[r] = xp[0]; xb[r] = xp[1];
          }
          #pragma unroll
          for (int s = 0; s < 5; ++s){
            uint4 u = uc[s];
            float w0=bf_lo(u.x), w1=bf_hi(u.x), w2=bf_lo(u.y), w3=bf_hi(u.y);
            float w4=bf_lo(u.z), w5=bf_hi(u.z), w6=bf_lo(u.w), w7=bf_hi(u.w);
            #pragma unroll
            for (int r = 0; r < 4; ++r){
              a2[s][r] += xa[r].x*w0 + xa[r].y*w1 + xa[r].z*w2 + xa[r].w*w3
                        + xb[r].x*w4 + xb[r].y*w5 + xb[r].z*w6 + xb[r].w*w7;
            }
          }
          #pragma unroll
          for (int s = 0; s < 5; ++s) uc[s] = un[s];
        }
      }
      #pragma unroll
      for (int s = 0; s < 5; ++s){
        int n = ln + (s << 6);
        if (s < 4 || n < NH3){
          #pragma unroll
          for (int r = 0; r < 4; ++r){
            float g1 = a1[s][r] + bih_s[n];
            float g2 = a2[s][r] + bhh_s[n];
            if (n < 200) Srz[r0w + r][n] = g1 + g2;
            else { gxn[r0w + r][n - 200] = g1; ghn[r0w + r][n - 200] = g2; }
          }
        }
      }
    }
    __syncthreads();

    // stage3: gates + h update
    for (int p = 0; p < 7; ++p){
      int idx = tid + (p << 8);
      if (idx < RPB*100){
        int r = idx / 100, j = idx - r*100;
        float rr = 1.f/(1.f + expf(-Srz[r][j]));
        float zz = 1.f/(1.f + expf(-Srz[r][100 + j]));
        float nn = tanhf(gxn[r][j] + rr*ghn[r][j]);
        hS[r][j] = (1.f - zz)*nn + zz*hS[r][j];
      }
    }
    __syncthreads();

    // stage4: hn2 = tanh(h@Wl1+bl1)
    for (int p = 0; p < 7; ++p){
      int idx = tid + (p << 8);
      if (idx < RPB*100){
        int r = idx / 100, j = idx - r*100;
        hn2[r][j] = tanhf(bl1_s[j] + dotblk(&hS[r][0], P.Wl1, j, 100, 13));
      }
    }
    __syncthreads();

    // stage5: out_t = hn2@Wl2+bl2 -> oS window + yprev regs
    #pragma unroll
    for (int p = 0; p < 4; ++p){
      int idx = tid + (p << 8);
      int r = idx >> 6, d = idx & 63;
      float o = bl2_s[d] + dotblk(&hn2[r][0], P.Wl2, d, 64, 13);
      oS[r][d][tc] = f2bf(o);
      yprev[p] = o;
    }
    __syncthreads();
  }

  // final window flush (t = 196..199)
  {
    int tw = TT - 4;
    #pragma unroll
    for (int p = 0; p < 4; ++p){
      int idx = tid + (p << 8);
      int r = idx >> 6, d = idx & 63;
      size_t base = ((size_t)(row0 + r)*64 + d)*200 + tw;
      if (fmode == 0){
        uint2 v = *(const uint2*)&oS[r][d][0];
        *(uint2*)((u16*)P.out + base) = v;
      } else {
        float4 f;
        f.x = __uint_as_float((u32)oS[r][d][0] << 16);
        f.y = __uint_as_float((u32)oS[r][d][1] << 16);
        f.z = __uint_as_float((u32)oS[r][d][2] << 16);
        f.w = __uint_as_float((u32)oS[r][d][3] << 16);
        *(float4*)((float*)P.out + base) = f;
      }
    }
  }

  // classifier: sigmoid(relu(h@Wc1+bc1)@Wc2+bc2)
  for (int p = 0; p < 4; ++p){
    int idx = tid + (p << 8);
    if (idx < RPB*50){
      int r = idx / 50, j = idx - r*50;
      float c = bc1_s[j] + dotblk(&hS[r][0], P.Wc1, j, 50, 13);
      gxn[r][j] = fmaxf(c, 0.f);
    }
  }
  __syncthreads();
  if (tid < RPB){
    float oc = loadf(P.bc2, 0, fmode);
    for (int j = 0; j < 50; ++j) oc += gxn[tid][j]*wc2_s[j];
    float sg = 1.f/(1.f + expf(-oc));
    size_t off = (size_t)BSZ*YD*TT + row0 + tid;
    if (fmode == 0) ((u16*)P.out)[off] = f2bf(sg);
    else            ((float*)P.out)[off] = sg;
  }
}

extern "C" void kernel_launch(void* const* d_in, const int* in_sizes, int n_in,
                              void* d_out, int out_size, void* d_ws, size_t ws_size,
                              hipStream_t stream){
  // ws layout: [0..256): flags; then blocked bf16 weights (~230 KB total)
  int* flags = (int*)d_ws;
  u16* wb = (u16*)((char*)d_ws + 256);
  u16* Wih  = wb;            // 16*300*8
  u16* Whh  = wb + 38400;    // 13*300*8
  u16* Wl1  = wb + 69600;    // 13*100*8
  u16* Wl2  = wb + 80000;    // 13*64*8
  u16* Wmu1 = wb + 86656;    // 16*100*8
  u16* Wmu2 = wb + 99456;    // 13*100*8
  u16* Wc1  = wb + 109856;   // 13*50*8

  detect_kernel<<<2, 256, 0, stream>>>(d_in[2], d_in[0], flags);

  WtP wp;
  wp.flags = flags;
  wp.src[0] = d_in[11]; wp.dst[0] = Wih;
  wp.src[1] = d_in[13]; wp.dst[1] = Whh;
  wp.src[2] = d_in[15]; wp.dst[2] = Wl1;
  wp.src[3] = d_in[17]; wp.dst[3] = Wl2;
  wp.src[4] = d_in[3];  wp.dst[4] = Wmu1;
  wp.src[5] = d_in[5];  wp.dst[5] = Wmu2;
  wp.src[6] = d_in[19]; wp.dst[6] = Wc1;
  wtrans_kernel<<<56, 256, 0, stream>>>(wp);

  MainP mp;
  mp.x = d_in[0]; mp.y = d_in[1]; mp.mask = d_in[2];
  mp.bmu1 = d_in[4];  mp.bmu2 = d_in[6];
  mp.bih  = d_in[12]; mp.bhh  = d_in[14];
  mp.bl1  = d_in[16]; mp.bl2  = d_in[18];
  mp.bc1  = d_in[20]; mp.bc2  = d_in[22]; mp.wc2 = d_in[21];
  mp.Wih = Wih; mp.Whh = Whh; mp.Wl1 = Wl1; mp.Wl2 = Wl2;
  mp.Wmu1 = Wmu1; mp.Wmu2 = Wmu2; mp.Wc1 = Wc1;
  mp.flags = flags; mp.out = d_out;
  gru_main<<<NBLK, 256, 0, stream>>>(mp);
}

// Round 2
// 1502.101 us; speedup vs baseline: 4.7137x; 4.7137x over previous
//
#include <hip/hip_runtime.h>
#include <hip/hip_bf16.h>

// GRU_teach round 1: MFMA persistent kernel.
// - 256 blocks x 256 threads, 16 rows/block, 200 steps, no grid sync.
// - All 4 per-step GEMMs on v_mfma_f32_16x16x32_bf16; weight B-fragments
//   pre-packed by fragk and held in 208 VGPRs/lane for the whole t-loop.
// - y/mask: 8-step register windows via uint4 (line reuse through L2).
// - out: 16-step LDS window, flushed as 2x uint4 per (r,d) -> full-line writes.
// - y_prev feedback read from the bf16 out window (same precision as x_il).

#define BSZ   4096
#define XD    128
#define YD    64
#define TT    200
#define NH3   300
#define RPB   16
#define NBLK  (BSZ / RPB)

typedef unsigned short u16;
typedef unsigned int   u32;
typedef __attribute__((ext_vector_type(8))) short s16x8;
typedef __attribute__((ext_vector_type(4))) float f32x4;

__device__ __forceinline__ float bf_lo(u32 u){ return __uint_as_float(u << 16); }
__device__ __forceinline__ float bf_hi(u32 u){ return __uint_as_float(u & 0xFFFF0000u); }
__device__ __forceinline__ u16 f2bf(float f){
  u32 u = __float_as_uint(f);
  u32 r = (u + 0x7FFFu + ((u >> 16) & 1u)) >> 16;   // RNE
  return (u16)r;
}
__device__ __forceinline__ float loadf(const void* p, size_t i, int fmode){
  return (fmode == 0) ? __uint_as_float(((u32)((const u16*)p)[i]) << 16)
                      : ((const float*)p)[i];
}
__device__ __forceinline__ float fsig(float x){ return 1.f/(1.f + __expf(-x)); }
__device__ __forceinline__ float ftanh(float x){ float e = __expf(2.f*x); return 1.f - 2.f/(e + 1.f); }

__device__ __forceinline__ f32x4 mfma16(uint4 a, uint4 b, f32x4 c){
  s16x8 as, bs;
  __builtin_memcpy(&as, &a, 16);
  __builtin_memcpy(&bs, &b, 16);
  return __builtin_amdgcn_mfma_f32_16x16x32_bf16(as, bs, c, 0, 0, 0);
}

// dot of fp32 LDS row (KB*8 floats, zero-padded) with k-blocked bf16 weights, column n of N
__device__ __forceinline__ float dotblk(const float* xr, const u16* wb, int n, int N, int KB){
  float a = 0.f;
  const uint4* wp = (const uint4*)wb;
  #pragma unroll
  for (int kb = 0; kb < KB; ++kb){
    uint4 u = wp[kb * N + n];
    const float4* xp = (const float4*)(xr + (kb << 3));
    float4 x0 = xp[0], x1 = xp[1];
    a += x0.x*bf_lo(u.x) + x0.y*bf_hi(u.x) + x0.z*bf_lo(u.y) + x0.w*bf_hi(u.y);
    a += x1.x*bf_lo(u.z) + x1.y*bf_hi(u.z) + x1.z*bf_lo(u.w) + x1.w*bf_hi(u.w);
  }
  return a;
}

// ---------------- dtype detection (unchanged from round 0 —验证过) ----------------
__global__ void detect_kernel(const void* mask, const void* x, int* flags){
  __shared__ int cnt[4];
  if (threadIdx.x < 4) cnt[threadIdx.x] = 0;
  __syncthreads();
  if (blockIdx.x == 0){
    const unsigned char* p = (const unsigned char*)mask;
    int c0=0, c1=0, c2=0, c3=0;
    for (int i = threadIdx.x; i < 4096; i += 256){
      unsigned char b = p[i];
      if (b == 0x3F && (i & 3) == 1) c0++;
      if (b == 0x3F && (i & 3) == 3) c1++;
      if (b == 1    && (i & 3) != 0) c2++;
      if (b == 1)                    c3++;
    }
    atomicAdd(&cnt[0], c0); atomicAdd(&cnt[1], c1);
    atomicAdd(&cnt[2], c2); atomicAdd(&cnt[3], c3);
    __syncthreads();
    if (threadIdx.x == 0){
      int mm;
      if      (cnt[0] > 0) mm = 0;
      else if (cnt[1] > 0) mm = 1;
      else if (cnt[2] > 0) mm = 3;
      else if (cnt[3] > 0) mm = 2;
      else                 mm = 0;
      flags[1] = mm;
    }
  } else {
    const u16* u = (const u16*)x;
    int c = 0;
    for (int i = threadIdx.x; i < 4096; i += 256){
      int ex = (u[i] >> 7) & 0xFF;
      if (ex >= 147) c++;
    }
    atomicAdd(&cnt[0], c);
    __syncthreads();
    if (threadIdx.x == 0) flags[0] = (cnt[0] > 32) ? 1 : 0;
  }
}

// -------- blocked repack for VALU paths (Wmu1, Wmu2, Wc1): [K][N] -> [kb][N][8] bf16 --------
struct WtP { const void* src[3]; u16* dst[3]; const int* flags; };

__global__ void wtrans_kernel(WtP a){
  const int Ks[3]  = {128, 100, 100};
  const int Ns[3]  = {100, 100,  50};
  const int KBs[3] = { 16,  13,  13};
  int m   = blockIdx.x >> 3;
  int sub = blockIdx.x & 7;
  int K = Ks[m], N = Ns[m], KB = KBs[m];
  const void* src = a.src[m];
  u16* dst = a.dst[m];
  int fmode = a.flags[0];
  int E = KB * N * 8;
  for (int e = sub*256 + threadIdx.x; e < E; e += 8*256){
    int idx = e >> 3, kc = e & 7;
    int n = idx % N, kb = idx / N;
    int k = kb*8 + kc;
    float v = (k < K) ? loadf(src, (size_t)k * N + n, fmode) : 0.f;
    dst[e] = f2bf(v);
  }
}

// -------- MFMA B-fragment repack: frag[nt][kc][lane][8] with B[k][n], n=lane&15, k=kc*32+(lane>>4)*8+j --------
struct FrP { const void* src[4]; u16* dst[4]; const int* flags; };

__global__ void fragk(FrP a){
  const int Ks[4]  = {128, 100, 100, 100};
  const int Ns[4]  = {300, 300, 100,  64};
  const int NTs[4] = { 20,  20,   8,   4};
  int m   = blockIdx.x >> 3;
  int sub = blockIdx.x & 7;
  int K = Ks[m], N = Ns[m];
  const void* src = a.src[m];
  u16* dst = a.dst[m];
  int fmode = a.flags[0];
  int E = NTs[m] * 2048;
  for (int e = sub*256 + threadIdx.x; e < E; e += 8*256){
    int j    = e & 7;
    int lane = (e >> 3) & 63;
    int kc   = (e >> 9) & 3;
    int nt   = e >> 11;
    int k = kc*32 + ((lane >> 4) << 3) + j;
    int n = nt*16 + (lane & 15);
    float v = (k < K && n < N) ? loadf(src, (size_t)k * N + n, fmode) : 0.f;
    dst[e] = f2bf(v);
  }
}

// ---------------- main persistent kernel ----------------
struct MainP {
  const void *x, *y, *mask;
  const void *bmu1, *bmu2, *bih, *bhh, *bl1, *bl2, *bc1, *bc2, *wc2;
  const u16 *Wmu1b, *Wmu2b, *Wc1b;
  const u16 *fih, *fhh, *fl1, *fl2;
  const int* flags;
  void* out;
};

__device__ __forceinline__ void load_win8(const void* Y, const void* M, int row0, int t,
                                          int fmode, int mmode, uint4* yv, u32& mb){
  mb = 0u;
  #pragma unroll
  for (int p = 0; p < 4; ++p){
    int idx = threadIdx.x + (p << 8);
    int r = idx >> 6, d = idx & 63;
    size_t base = ((size_t)(row0 + r)*64 + d)*200 + t;
    uint4 yw;
    if (fmode == 0){
      yw = *(const uint4*)((const u16*)Y + base);
    } else {
      const float* yf = (const float*)Y + base;
      float4 f0 = *(const float4*)yf;
      float4 f1 = *(const float4*)(yf + 4);
      yw.x = (u32)f2bf(f0.x) | ((u32)f2bf(f0.y) << 16);
      yw.y = (u32)f2bf(f0.z) | ((u32)f2bf(f0.w) << 16);
      yw.z = (u32)f2bf(f1.x) | ((u32)f2bf(f1.y) << 16);
      yw.w = (u32)f2bf(f1.z) | ((u32)f2bf(f1.w) << 16);
    }
    yv[p] = yw;
    u32 bits = 0;
    if (mmode == 0){
      uint4 mw = *(const uint4*)((const u16*)M + base);
      u32 w0 = mw.x, w1 = mw.y, w2 = mw.z, w3 = mw.w;
      if (w0 & 0xFFFFu) bits |= 1u;  if (w0 >> 16) bits |= 2u;
      if (w1 & 0xFFFFu) bits |= 4u;  if (w1 >> 16) bits |= 8u;
      if (w2 & 0xFFFFu) bits |= 16u; if (w2 >> 16) bits |= 32u;
      if (w3 & 0xFFFFu) bits |= 64u; if (w3 >> 16) bits |= 128u;
    } else if (mmode == 1){
      const float* mf = (const float*)M + base;
      float4 f0 = *(const float4*)mf;
      float4 f1 = *(const float4*)(mf + 4);
      if (f0.x != 0.f) bits |= 1u;  if (f0.y != 0.f) bits |= 2u;
      if (f0.z != 0.f) bits |= 4u;  if (f0.w != 0.f) bits |= 8u;
      if (f1.x != 0.f) bits |= 16u; if (f1.y != 0.f) bits |= 32u;
      if (f1.z != 0.f) bits |= 64u; if (f1.w != 0.f) bits |= 128u;
    } else if (mmode == 2){
      const int* mi = (const int*)M + base;
      int4 v0 = *(const int4*)mi;
      int4 v1 = *(const int4*)(mi + 4);
      if (v0.x) bits |= 1u;  if (v0.y) bits |= 2u;
      if (v0.z) bits |= 4u;  if (v0.w) bits |= 8u;
      if (v1.x) bits |= 16u; if (v1.y) bits |= 32u;
      if (v1.z) bits |= 64u; if (v1.w) bits |= 128u;
    } else {
      uint2 u = *(const uint2*)((const unsigned char*)M + base);
      #pragma unroll
      for (int q = 0; q < 4; ++q){
        if ((u.x >> (q*8)) & 0xFFu) bits |= 1u << q;
        if ((u.y >> (q*8)) & 0xFFu) bits |= 1u << (4 + q);
      }
    }
    mb |= bits << (p << 3);
  }
}

__global__ __launch_bounds__(256, 1) void gru_main(MainP P){
  __shared__ u16   XIL[RPB*136];     // x_il bf16, row stride 136
  __shared__ u16   HB [RPB*136];     // h bf16 (A operand), pads zeroed
  __shared__ u16   HN2[RPB*136];     // tanh(h@Wl1+bl1) bf16
  __shared__ float HF [RPB*108];     // h fp32
  __shared__ float SRZ[RPB*204];     // r|z preacts (also fp32 x staging in prologue)
  __shared__ float GXN[RPB*108];
  __shared__ float GHN[RPB*108];
  __shared__ u16   OS [RPB*64*16];   // out window: [r][d][slot]
  __shared__ float BIH[304], BHH[304], BL1[128], BL2[64], BC1[64], WC2[64], BMU1[112], BMU2[112];

  const int tid  = threadIdx.x;
  const int row0 = blockIdx.x * RPB;
  const int fmode = P.flags[0];
  const int mmode = P.flags[1];
  const int w  = tid >> 6;
  const int ln = tid & 63;
  const int col = ln & 15;
  const int q4  = (ln >> 4) << 2;

  // y/mask windows (8 steps)
  uint4 yc[4], yn[4];
  u32 mc, mn;
  load_win8(P.y, P.mask, row0, 0, fmode, mmode, yc, mc);
  load_win8(P.y, P.mask, row0, 8, fmode, mmode, yn, mn);

  // weight fragments -> registers (held across the whole t-loop)
  uint4 wih[5][4], whh[5][4], wl1[2][4], wl2[4];
  #pragma unroll
  for (int i = 0; i < 5; ++i){
    int nt = w + 4*i;
    #pragma unroll
    for (int kc = 0; kc < 4; ++kc){
      wih[i][kc] = *(const uint4*)(P.fih + (((nt*4 + kc) << 6) + ln)*8);
      whh[i][kc] = *(const uint4*)(P.fhh + (((nt*4 + kc) << 6) + ln)*8);
    }
  }
  #pragma unroll
  for (int i = 0; i < 2; ++i){
    int nt = w + 4*i;
    #pragma unroll
    for (int kc = 0; kc < 4; ++kc)
      wl1[i][kc] = *(const uint4*)(P.fl1 + (((nt*4 + kc) << 6) + ln)*8);
  }
  #pragma unroll
  for (int kc = 0; kc < 4; ++kc)
    wl2[kc] = *(const uint4*)(P.fl2 + (((w*4 + kc) << 6) + ln)*8);

  // zero LDS (pads + initial state)
  for (int i = tid; i < RPB*136/2; i += 256){ ((u32*)HB)[i] = 0u; ((u32*)HN2)[i] = 0u; }
  for (int i = tid; i < RPB*108;   i += 256){ HF[i] = 0.f; GXN[i] = 0.f; GHN[i] = 0.f; }
  for (int i = tid; i < RPB*64*8;  i += 256){ ((u32*)OS)[i] = 0u; }

  // biases
  for (int i = tid; i < 304; i += 256){
    BIH[i] = (i < 300) ? loadf(P.bih, i, fmode) : 0.f;
    BHH[i] = (i < 300) ? loadf(P.bhh, i, fmode) : 0.f;
  }
  if (tid < 128) BL1[tid] = (tid < 100) ? loadf(P.bl1, tid, fmode) : 0.f;
  if (tid < 64){
    BL2[tid] = loadf(P.bl2, tid, fmode);
    BC1[tid] = (tid < 50) ? loadf(P.bc1, tid, fmode) : 0.f;
    WC2[tid] = (tid < 50) ? loadf(P.wc2, tid, fmode) : 0.f;
  }
  if (tid < 112){
    BMU1[tid] = (tid < 100) ? loadf(P.bmu1, tid, fmode) : 0.f;
    BMU2[tid] = (tid < 100) ? loadf(P.bmu2, tid, fmode) : 0.f;
  }
  __syncthreads();

  // ---- prologue h0 = tanh(x@Wmu1+bmu1)@Wmu2+bmu2 (VALU, once) ----
  #pragma unroll
  for (int p = 0; p < 2; ++p){
    int idx = tid + (p << 8);
    int r = idx >> 5, kq = idx & 31;
    size_t base = ((size_t)(row0 + r) << 7) + ((size_t)kq << 2);
    float v0, v1, v2, v3;
    if (fmode == 0){
      uint2 u = *(const uint2*)((const u16*)P.x + base);
      v0 = bf_lo(u.x); v1 = bf_hi(u.x); v2 = bf_lo(u.y); v3 = bf_hi(u.y);
    } else {
      float4 f = *(const float4*)((const float*)P.x + base);
      v0 = f.x; v1 = f.y; v2 = f.z; v3 = f.w;
    }
    float* dst = &SRZ[r*204 + (kq << 2)];
    dst[0] = v0; dst[1] = v1; dst[2] = v2; dst[3] = v3;
  }
  __syncthreads();
  for (int p = 0; p < 7; ++p){
    int idx = tid + (p << 8);
    if (idx < RPB*100){
      int r = idx / 100, j = idx - r*100;
      GXN[r*108 + j] = ftanh(BMU1[j] + dotblk(&SRZ[r*204], P.Wmu1b, j, 100, 16));
    }
  }
  __syncthreads();
  for (int p = 0; p < 7; ++p){
    int idx = tid + (p << 8);
    if (idx < RPB*100){
      int r = idx / 100, j = idx - r*100;
      float hv = BMU2[j] + dotblk(&GXN[r*108], P.Wmu2b, j, 100, 13);
      HF[r*108 + j] = hv;
      HB[r*136 + j] = f2bf(hv);
    }
  }
  __syncthreads();

  // ---- t-loop ----
  for (int t = 0; t < TT; ++t){
    const int tc8 = t & 7;

    if (tc8 == 0 && t){
      #pragma unroll
      for (int p = 0; p < 4; ++p) yc[p] = yn[p];
      mc = mn;
      if (t + 8 < TT) load_win8(P.y, P.mask, row0, t + 8, fmode, mmode, yn, mn);
    }
    if ((t & 15) == 0 && t){
      // flush out window t-16..t-1 (full 32B per (r,d) row -> full-line HBM writes)
      int t0 = t - 16;
      #pragma unroll
      for (int p = 0; p < 4; ++p){
        int idx = tid + (p << 8);
        int r = idx >> 6, d = idx & 63;
        size_t base = ((size_t)(row0 + r)*64 + d)*200 + t0;
        const uint4* po = (const uint4*)&OS[(r*64 + d)*16];
        if (fmode == 0){
          u16* ob = (u16*)P.out + base;
          *(uint4*)ob = po[0];
          *(uint4*)(ob + 8) = po[1];
        } else {
          float* of = (float*)P.out + base;
          uint4 a = po[0], b = po[1];
          float4 f0 = {bf_lo(a.x), bf_hi(a.x), bf_lo(a.y), bf_hi(a.y)};
          float4 f1 = {bf_lo(a.z), bf_hi(a.z), bf_lo(a.w), bf_hi(a.w)};
          float4 f2 = {bf_lo(b.x), bf_hi(b.x), bf_lo(b.y), bf_hi(b.y)};
          float4 f3 = {bf_lo(b.z), bf_hi(b.z), bf_lo(b.w), bf_hi(b.w)};
          *(float4*)of = f0; *(float4*)(of+4) = f1;
          *(float4*)(of+8) = f2; *(float4*)(of+12) = f3;
        }
      }
    }

    // stage1: build x_il (teacher forcing; y_prev from bf16 out window)
    #pragma unroll
    for (int p = 0; p < 4; ++p){
      int idx = tid + (p << 8);
      int r = idx >> 6, d = idx & 63;
      u32 w01 = (tc8 & 2) ? yc[p].y : yc[p].x;
      u32 w23 = (tc8 & 2) ? yc[p].w : yc[p].z;
      u32 word = (tc8 & 4) ? w23 : w01;
      u16 yv16 = (tc8 & 1) ? (u16)(word >> 16) : (u16)(word & 0xFFFFu);
      bool mv = (mc >> ((p << 3) | tc8)) & 1u;
      u16 yp16 = OS[(r*64 + d)*16 + ((t + 15) & 15)];
      u32 val = (u32)(mv ? yv16 : yp16) | ((mv ? 0x3F80u : 0u) << 16);
      *(u32*)(&XIL[r*136 + (d << 1)]) = val;
    }
    __syncthreads();

    // stage2: gx = x_il@Wih, gh = h@Whh (MFMA)
    {
      uint4 xa[4], ha[4];
      #pragma unroll
      for (int kc = 0; kc < 4; ++kc){
        int ao = (ln & 15)*136 + kc*32 + ((ln >> 4) << 3);
        xa[kc] = *(const uint4*)(&XIL[ao]);
        ha[kc] = *(const uint4*)(&HB[ao]);
      }
      #pragma unroll
      for (int i = 0; i < 3; ++i){          // nt <= 11: all cols < 200, shared acc
        f32x4 ac = {0.f, 0.f, 0.f, 0.f};
        #pragma unroll
        for (int kc = 0; kc < 4; ++kc) ac = mfma16(xa[kc], wih[i][kc], ac);
        #pragma unroll
        for (int kc = 0; kc < 4; ++kc) ac = mfma16(ha[kc], whh[i][kc], ac);
        int n = (w + 4*i)*16 + col;
        float bb = BIH[n] + BHH[n];
        #pragma unroll
        for (int reg = 0; reg < 4; ++reg)
          SRZ[(q4 + reg)*204 + n] = ac[reg] + bb;
      }
      #pragma unroll
      for (int i = 3; i < 5; ++i){          // nt 12..19: may split r/z vs n-gate
        f32x4 ax = {0.f,0.f,0.f,0.f}, ah = {0.f,0.f,0.f,0.f};
        #pragma unroll
        for (int kc = 0; kc < 4; ++kc){
          ax = mfma16(xa[kc], wih[i][kc], ax);
          ah = mfma16(ha[kc], whh[i][kc], ah);
        }
        int n = (w + 4*i)*16 + col;
        if (n < 200){
          float bb = BIH[n] + BHH[n];
          #pragma unroll
          for (int reg = 0; reg < 4; ++reg)
            SRZ[(q4 + reg)*204 + n] = ax[reg] + ah[reg] + bb;
        } else if (n < 304){
          float b1 = BIH[n], b2 = BHH[n];
          #pragma unroll
          for (int reg = 0; reg < 4; ++reg){
            GXN[(q4 + reg)*108 + n - 200] = ax[reg] + b1;
            GHN[(q4 + reg)*108 + n - 200] = ah[reg] + b2;
          }
        }
      }
    }
    __syncthreads();

    // stage3: gates + h update
    for (int p = 0; p < 7; ++p){
      int idx = tid + (p << 8);
      if (idx < RPB*100){
        int r = idx / 100, j = idx - r*100;
        float rr = fsig(SRZ[r*204 + j]);
        float zz = fsig(SRZ[r*204 + 100 + j]);
        float nn = ftanh(GXN[r*108 + j] + rr*GHN[r*108 + j]);
        float hv = (1.f - zz)*nn + zz*HF[r*108 + j];
        HF[r*108 + j] = hv;
        HB[r*136 + j] = f2bf(hv);
      }
    }
    __syncthreads();

    // stage4: hn2 = tanh(h@Wl1+bl1) (MFMA)
    {
      uint4 ha[4];
      #pragma unroll
      for (int kc = 0; kc < 4; ++kc){
        int ao = (ln & 15)*136 + kc*32 + ((ln >> 4) << 3);
        ha[kc] = *(const uint4*)(&HB[ao]);
      }
      #pragma unroll
      for (int i = 0; i < 2; ++i){
        f32x4 ac = {0.f,0.f,0.f,0.f};
        #pragma unroll
        for (int kc = 0; kc < 4; ++kc) ac = mfma16(ha[kc], wl1[i][kc], ac);
        int n = (w + 4*i)*16 + col;
        #pragma unroll
        for (int reg = 0; reg < 4; ++reg)
          HN2[(q4 + reg)*136 + n] = f2bf(ftanh(ac[reg] + BL1[n]));
      }
    }
    __syncthreads();

    // stage5: out_t = hn2@Wl2+bl2 (MFMA) -> out window
    {
      uint4 na[4];
      #pragma unroll
      for (int kc = 0; kc < 4; ++kc){
        int ao = (ln & 15)*136 + kc*32 + ((ln >> 4) << 3);
        na[kc] = *(const uint4*)(&HN2[ao]);
      }
      f32x4 ac = {0.f,0.f,0.f,0.f};
      #pragma unroll
      for (int kc = 0; kc < 4; ++kc) ac = mfma16(na[kc], wl2[kc], ac);
      int d = w*16 + col;
      #pragma unroll
      for (int reg = 0; reg < 4; ++reg){
        float o = ac[reg] + BL2[d];
        OS[((q4 + reg)*64 + d)*16 + (t & 15)] = f2bf(o);
      }
    }
    __syncthreads();
  }

  // final flush: t = 192..199 (slots 0..7 only)
  {
    int t0 = TT - 8;
    #pragma unroll
    for (int p = 0; p < 4; ++p){
      int idx = tid + (p << 8);
      int r = idx >> 6, d = idx & 63;
      size_t base = ((size_t)(row0 + r)*64 + d)*200 + t0;
      const uint4* po = (const uint4*)&OS[(r*64 + d)*16];
      if (fmode == 0){
        *(uint4*)((u16*)P.out + base) = po[0];
      } else {
        float* of = (float*)P.out + base;
        uint4 a = po[0];
        float4 f0 = {bf_lo(a.x), bf_hi(a.x), bf_lo(a.y), bf_hi(a.y)};
        float4 f1 = {bf_lo(a.z), bf_hi(a.z), bf_lo(a.w), bf_hi(a.w)};
        *(float4*)of = f0; *(float4*)(of+4) = f1;
      }
    }
  }

  // classifier: sigmoid(relu(h@Wc1+bc1)@Wc2+bc2)
  for (int p = 0; p < 4; ++p){
    int idx = tid + (p << 8);
    if (idx < RPB*50){
      int r = idx / 50, j = idx - r*50;
      float c = BC1[j] + dotblk(&HF[r*108], P.Wc1b, j, 50, 13);
      GXN[r*108 + j] = fmaxf(c, 0.f);
    }
  }
  __syncthreads();
  if (tid < RPB){
    float oc = loadf(P.bc2, 0, fmode);
    for (int j = 0; j < 50; ++j) oc += GXN[tid*108 + j]*WC2[j];
    float sg = fsig(oc);
    size_t off = (size_t)BSZ*YD*TT + row0 + tid;
    if (fmode == 0) ((u16*)P.out)[off] = f2bf(sg);
    else            ((float*)P.out)[off] = sg;
  }
}

extern "C" void kernel_launch(void* const* d_in, const int* in_sizes, int n_in,
                              void* d_out, int out_size, void* d_ws, size_t ws_size,
                              hipStream_t stream){
  // ws: [0..256) flags; then u16 region:
  //   Wmu1b 12800 | Wmu2b 10400 | Wc1b 5200 | fih 40960 | fhh 40960 | fl1 16384 | fl2 8192
  int* flags = (int*)d_ws;
  u16* wb = (u16*)((char*)d_ws + 256);
  u16* Wmu1b = wb;
  u16* Wmu2b = wb + 12800;
  u16* Wc1b  = wb + 23200;
  u16* fih   = wb + 28400;
  u16* fhh   = wb + 69360;
  u16* fl1   = wb + 110320;
  u16* fl2   = wb + 126704;

  detect_kernel<<<2, 256, 0, stream>>>(d_in[2], d_in[0], flags);

  WtP wp;
  wp.flags = flags;
  wp.src[0] = d_in[3];  wp.dst[0] = Wmu1b;
  wp.src[1] = d_in[5];  wp.dst[1] = Wmu2b;
  wp.src[2] = d_in[19]; wp.dst[2] = Wc1b;
  wtrans_kernel<<<24, 256, 0, stream>>>(wp);

  FrP fp;
  fp.flags = flags;
  fp.src[0] = d_in[11]; fp.dst[0] = fih;
  fp.src[1] = d_in[13]; fp.dst[1] = fhh;
  fp.src[2] = d_in[15]; fp.dst[2] = fl1;
  fp.src[3] = d_in[17]; fp.dst[3] = fl2;
  fragk<<<32, 256, 0, stream>>>(fp);

  MainP mp;
  mp.x = d_in[0]; mp.y = d_in[1]; mp.mask = d_in[2];
  mp.bmu1 = d_in[4];  mp.bmu2 = d_in[6];
  mp.bih  = d_in[12]; mp.bhh  = d_in[14];
  mp.bl1  = d_in[16]; mp.bl2  = d_in[18];
  mp.bc1  = d_in[20]; mp.bc2  = d_in[22]; mp.wc2 = d_in[21];
  mp.Wmu1b = Wmu1b; mp.Wmu2b = Wmu2b; mp.Wc1b = Wc1b;
  mp.fih = fih; mp.fhh = fhh; mp.fl1 = fl1; mp.fl2 = fl2;
  mp.flags = flags; mp.out = d_out;
  gru_main<<<NBLK, 256, 0, stream>>>(mp);
}